// Round 10
// baseline (249.345 us; speedup 1.0000x reference)
//
#include <hip/hip_runtime.h>

#define HW 16384   // 128*128

typedef __attribute__((ext_vector_type(8))) short short8;
typedef __attribute__((ext_vector_type(16))) float floatx16;
typedef __attribute__((ext_vector_type(4))) unsigned int uvec4;

__device__ inline unsigned short f2bf(float f) {
    unsigned u = __builtin_bit_cast(unsigned, f);
    u = (u + 0x7FFFu + ((u >> 16) & 1u)) >> 16;   // RNE
    return (unsigned short)u;
}

// pack two fp32 -> bf16x2 by truncation: one v_perm_b32
__device__ inline unsigned pack_bf_trunc(float lo, float hi) {
    return __builtin_amdgcn_perm(__builtin_bit_cast(unsigned, hi),
                                 __builtin_bit_cast(unsigned, lo), 0x07060302u);
}

__device__ inline unsigned short trunc_bf(float f) {
    return (unsigned short)(__builtin_bit_cast(unsigned, f) >> 16);
}

// ---------------------------------------------------------------------------
// Cast + transpose x: [b][c][p] fp32 -> xt[b][p][c] bf16 (xt in d_ws).
// Folds the W-cast into 80 of the 4096 blocks: Wb[320][256] bf16,
// rows 0-31 q (PRE-SCALED by log2e), 32-63 k, 64-319 v.
// ---------------------------------------------------------------------------
__global__ __launch_bounds__(256) void cast_xt_kernel(
    const float* __restrict__ x,
    const float* __restrict__ Wq, const float* __restrict__ Wk,
    const float* __restrict__ Wv, unsigned short* __restrict__ Wb,
    unsigned short* __restrict__ xt)
{
    __shared__ unsigned short T[64][66];
    const int tid = threadIdx.x;
    const int p0 = blockIdx.x * 64;
    const int c0 = blockIdx.y * 64;
    const int b  = blockIdx.z;

    if (b == 0 && blockIdx.y == 0 && blockIdx.x < 80) {   // folded castW
        int e0 = (blockIdx.x * 256 + tid) * 4;
        int row = e0 >> 8, col = e0 & 255;
        const float* src = (row < 32) ? (Wq + row * 256 + col)
                         : (row < 64) ? (Wk + (row - 32) * 256 + col)
                                      : (Wv + (row - 64) * 256 + col);
        float4 v = *(const float4*)src;
        if (row < 32) {   // q rows: fold log2(e)
            const float L2E = 1.4426950408889634f;
            v.x *= L2E; v.y *= L2E; v.z *= L2E; v.w *= L2E;
        }
        uint2 pk;
        pk.x = f2bf(v.x) | ((unsigned)f2bf(v.y) << 16);
        pk.y = f2bf(v.z) | ((unsigned)f2bf(v.w) << 16);
        *(uint2*)&Wb[e0] = pk;
    }

    #pragma unroll
    for (int i = 0; i < 4; i++) {
        int e = i * 256 + tid;
        int c = e >> 4, seg = e & 15;
        float4 v = *(const float4*)&x[((b * 256 + c0 + c) << 14) + p0 + seg * 4];
        ((unsigned*)&T[c][seg * 4])[0] = f2bf(v.x) | ((unsigned)f2bf(v.y) << 16);
        ((unsigned*)&T[c][seg * 4])[1] = f2bf(v.z) | ((unsigned)f2bf(v.w) << 16);
    }
    __syncthreads();
    #pragma unroll
    for (int i = 0; i < 2; i++) {
        int e = i * 256 + tid;
        int p = e >> 3, cs = e & 7;
        unsigned short t[8];
        #pragma unroll
        for (int j = 0; j < 8; j++) t[j] = T[cs * 8 + j][p];
        uint4 pk;
        pk.x = t[0] | ((unsigned)t[1] << 16);
        pk.y = t[2] | ((unsigned)t[3] << 16);
        pk.z = t[4] | ((unsigned)t[5] << 16);
        pk.w = t[6] | ((unsigned)t[7] << 16);
        *(uint4*)&xt[(((b << 14) + p0 + p) << 8) + c0 + cs * 8] = pk;
    }
}

// ---------------------------------------------------------------------------
// FUSED proj+attention v5b. One block per (bh, y). Per side (row / col):
//   1) proj: stage xt panel [128px][64c] per kc (proj-proven swizzle),
//      3 A-tiles of W read from global (tile0 = q8+k8+v0-15, tile1 = v16-47,
//      tile2 = v48-63+junk), 48 MFMA -> full K=256 reduction in registers.
//      R9 BUG FIX: ks loop must run 4 iterations (c = 2*ks+lh spans chunks
//      0..7 = all 64 ch per kc). With ks<2 only ch 0-31 of each kc were
//      contracted -> absmax 1.93.
//   2) extract: q-frag in-register (pack regs0-3 + shfl_xor(32), lh=0 lanes),
//      k -> Kl LDS [128px][8ch], v -> Vs[side] (attn's swizzle convention).
//   3) attention: identical to R7 v4 (in-reg softmax, per-kg pack->PV,
//      separate per-side accumulators, deferred normalization).
// D mapping (proj-proven): mfma(af=W,bf=xt) -> D[row=W-oc][col=px=lane],
// row = (reg&3)+8*(reg>>2)+4*lh.
// ---------------------------------------------------------------------------
__global__ __launch_bounds__(256, 2) void fused_kernel(
    const unsigned short* __restrict__ Wb, const unsigned short* __restrict__ xt,
    const float* __restrict__ bq, const float* __restrict__ bk,
    const float* __restrict__ bv,
    const float* __restrict__ xin, const float* __restrict__ gamma,
    float* __restrict__ out)
{
    __shared__ __align__(16) unsigned short XTS[128 * 64];     // 16KB xt panel
    __shared__ __align__(16) unsigned short Vs[2][64 * 128];   // 32KB [ch][key]
    __shared__ __align__(16) unsigned short Kl[128 * 8];       // 2KB [px][8ch]
    __shared__ float biasS[80];                                // q8|k8|v64

    const int tid = threadIdx.x;
    const int y = blockIdx.x >> 4, bh = blockIdx.x & 15;       // y-major: h/b-sharers adjacent
    const int b = bh >> 2, h = bh & 3;
    const int w = tid >> 6, l = tid & 63, lr = l & 31, lh = l >> 5;
    const int px = 32 * w + lr;

    if (tid < 80) biasS[tid] = (tid < 8)  ? bq[h * 8 + tid] * 1.4426950408889634f
                             : (tid < 16) ? bk[h * 8 + tid - 8]
                                          : bv[h * 64 + tid - 16];

    // per-lane W row indices for the 3 A-tiles
    const int wr0 = (lr < 8)  ? h * 8 + lr
                  : (lr < 16) ? 32 + h * 8 + (lr - 8)
                              : 64 + h * 64 + (lr - 16);
    const int wr1 = 64 + h * 64 + 16 + lr;
    const int wr2 = 64 + h * 64 + 48 + (lr & 15);   // lr>=16: junk rows (discarded)

    floatx16 z16 = {0,0,0,0,0,0,0,0,0,0,0,0,0,0,0,0};
    short8 z8 = {0,0,0,0,0,0,0,0};
    floatx16 oh0 = z16, oh1 = z16, ov0 = z16, ov1 = z16;
    float ssA = 1.0f, ssB = 1.0f;

    #pragma unroll
    for (int side = 0; side < 2; side++) {
        // ---------------- projection: K=256 reduction ----------------
        floatx16 a0 = z16, a1 = z16, a2 = z16;
        for (int kc = 0; kc < 4; kc++) {
            __syncthreads();   // XTS (and cross-side Kl/Vs) safe to write
            #pragma unroll
            for (int i = 0; i < 4; i++) {
                int e = i * 256 + tid;
                int row = e >> 3, seg = e & 7, cp = seg ^ (row & 7);
                int p = side ? (row * 128 + y) : (y * 128 + row);
                *(uint4*)&XTS[row * 64 + cp * 8] =
                    *(const uint4*)&xt[(((b << 14) + p) << 8) + kc * 64 + seg * 8];
            }
            __syncthreads();
            #pragma unroll
            for (int ks = 0; ks < 4; ks++) {   // FIX: 4 (was 2) -> full 64ch/kc
                int cx = ((2 * ks + lh) ^ (lr & 7)) * 8;
                short8 bfr = *(const short8*)&XTS[px * 64 + cx];
                int ck = kc * 64 + (2 * ks + lh) * 8;
                short8 af0 = *(const short8*)&Wb[wr0 * 256 + ck];
                short8 af1 = *(const short8*)&Wb[wr1 * 256 + ck];
                short8 af2 = *(const short8*)&Wb[wr2 * 256 + ck];
                a0 = __builtin_amdgcn_mfma_f32_32x32x16_bf16(af0, bfr, a0, 0, 0, 0);
                a1 = __builtin_amdgcn_mfma_f32_32x32x16_bf16(af1, bfr, a1, 0, 0, 0);
                a2 = __builtin_amdgcn_mfma_f32_32x32x16_bf16(af2, bfr, a2, 0, 0, 0);
            }
        }
        // ---------------- extract q / k / v ----------------
        // q: tile0 rows 0-7 = regs 0-3 (+4lh). lh=0 lane needs ch0-7:
        // words = [own(ch 0-3), partner(ch 4-7)] via shfl_xor(32).
        unsigned X0 = pack_bf_trunc(a0[0] + biasS[4 * lh + 0], a0[1] + biasS[4 * lh + 1]);
        unsigned X1 = pack_bf_trunc(a0[2] + biasS[4 * lh + 2], a0[3] + biasS[4 * lh + 3]);
        unsigned pX0 = __shfl_xor(X0, 32), pX1 = __shfl_xor(X1, 32);
        short8 bfq = z8;
        if (lh == 0) {
            uvec4 t; t.x = X0; t.y = X1; t.z = pX0; t.w = pX1;
            bfq = __builtin_bit_cast(short8, t);
        }
        // k: tile0 rows 8-15 = regs 4-7 -> Kl[px][8ch] (uint2 per lane, lh-half)
        {
            uint2 kk;
            kk.x = pack_bf_trunc(a0[4] + biasS[8 + 4 * lh + 0], a0[5] + biasS[8 + 4 * lh + 1]);
            kk.y = pack_bf_trunc(a0[6] + biasS[8 + 4 * lh + 2], a0[7] + biasS[8 + 4 * lh + 3]);
            *(uint2*)&Kl[px * 8 + 4 * lh] = kk;
        }
        // v: tile0 rows 16-31 (regs 8-15) = ch 0-15; tile1 = ch 16-47;
        //    tile2 regs 0-7 = ch 48-63. Vs[side][ch][key px], chunk ^= (ch&15).
        #pragma unroll
        for (int reg = 8; reg < 16; reg++) {
            int ch = (reg & 3) + 8 * ((reg >> 2) - 2) + 4 * lh;
            Vs[side][ch * 128 + (((px >> 3) ^ (ch & 15)) << 3) + (px & 7)] =
                trunc_bf(a0[reg] + biasS[16 + ch]);
        }
        #pragma unroll
        for (int reg = 0; reg < 16; reg++) {
            int ch = 16 + (reg & 3) + 8 * (reg >> 2) + 4 * lh;
            Vs[side][ch * 128 + (((px >> 3) ^ (ch & 15)) << 3) + (px & 7)] =
                trunc_bf(a1[reg] + biasS[16 + ch]);
        }
        #pragma unroll
        for (int reg = 0; reg < 8; reg++) {
            int ch = 48 + (reg & 3) + 8 * (reg >> 2) + 4 * lh;
            Vs[side][ch * 128 + (((px >> 3) ^ (ch & 15)) << 3) + (px & 7)] =
                trunc_bf(a2[reg] + biasS[16 + ch]);
        }
        __syncthreads();   // Kl/Vs[side] visible to all waves
        // ---------------- attention (R7 v4 structure) ----------------
        float partial = 0.f;
        #pragma unroll
        for (int kg = 0; kg < 4; kg++) {
            short8 af = z8;
            if (lh == 0) af = *(const short8*)&Kl[(32 * kg + lr) * 8];
            floatx16 e = __builtin_amdgcn_mfma_f32_32x32x16_bf16(af, bfq, z16, 0, 0, 0);
            #pragma unroll
            for (int r = 0; r < 16; r++) {
                float p = exp2f(e[r]);   // L2E folded into q; no max-pass (|e| small)
                e[r] = p;
                partial += p;
            }
            #pragma unroll
            for (int cc = 0; cc < 2; cc++) {
                unsigned Y0 = pack_bf_trunc(e[8*cc+0], e[8*cc+1]);
                unsigned Y1 = pack_bf_trunc(e[8*cc+2], e[8*cc+3]);
                unsigned Y2 = pack_bf_trunc(e[8*cc+4], e[8*cc+5]);
                unsigned Y3 = pack_bf_trunc(e[8*cc+6], e[8*cc+7]);
                unsigned pY0 = __shfl_xor(Y0, 32);
                unsigned pY1 = __shfl_xor(Y1, 32);
                unsigned pY2 = __shfl_xor(Y2, 32);
                unsigned pY3 = __shfl_xor(Y3, 32);
                uvec4 t;
                t.x = lh ? pY2 : Y0;
                t.y = lh ? pY3 : Y1;
                t.z = lh ? Y2  : pY0;
                t.w = lh ? Y3  : pY1;
                short8 pf = __builtin_bit_cast(short8, t);
                int ks = 2 * kg + cc;
                int cp = ((2 * ks + lh) ^ (lr & 15)) * 8;
                short8 v0 = *(const short8*)&Vs[side][lr * 128 + cp];
                short8 v1 = *(const short8*)&Vs[side][(32 + lr) * 128 + cp];
                if (side == 0) {
                    oh0 = __builtin_amdgcn_mfma_f32_32x32x16_bf16(v0, pf, oh0, 0, 0, 0);
                    oh1 = __builtin_amdgcn_mfma_f32_32x32x16_bf16(v1, pf, oh1, 0, 0, 0);
                } else {
                    ov0 = __builtin_amdgcn_mfma_f32_32x32x16_bf16(v0, pf, ov0, 0, 0, 0);
                    ov1 = __builtin_amdgcn_mfma_f32_32x32x16_bf16(v1, pf, ov1, 0, 0, 0);
                }
            }
        }
        float ssum = partial + __shfl_xor(partial, 32);
        if (side == 0) ssA = ssum; else ssB = ssum;
    }

    __syncthreads();   // re-converge waves: adjacent 128B out-stores coalesce

    const float g  = gamma[0];
    const float g0 = g / ssA, g1 = g / ssB;
    #pragma unroll
    for (int reg = 0; reg < 16; reg++) {
        int ch = (reg & 3) + 8 * (reg >> 2) + 4 * lh;
        int idx0 = (bh * 64 + ch) * HW + y * 128 + px;
        int idx1 = (bh * 64 + 32 + ch) * HW + y * 128 + px;
        out[idx0] = g0 * oh0[reg] + g1 * ov0[reg] + xin[idx0];
        out[idx1] = g0 * oh1[reg] + g1 * ov1[reg] + xin[idx1];
    }
}

extern "C" void kernel_launch(void* const* d_in, const int* in_sizes, int n_in,
                              void* d_out, int out_size, void* d_ws, size_t ws_size,
                              hipStream_t stream) {
    const float* x     = (const float*)d_in[0];
    const float* Wq    = (const float*)d_in[1];
    const float* bq    = (const float*)d_in[2];
    const float* Wk    = (const float*)d_in[3];
    const float* bk    = (const float*)d_in[4];
    const float* Wv    = (const float*)d_in[5];
    const float* bv    = (const float*)d_in[6];
    const float* gamma = (const float*)d_in[7];
    float* out = (float*)d_out;

    unsigned short* Wb = (unsigned short*)d_ws;
    unsigned short* xt = Wb + 320 * 256;   // xt in WORKSPACE: out is written
                                           // while other blocks still read xt.

    cast_xt_kernel<<<dim3(256, 4, 4), 256, 0, stream>>>(x, Wq, Wk, Wv, Wb, xt);
    fused_kernel<<<dim3(2048), 256, 0, stream>>>(Wb, xt, bq, bk, bv, x, gamma, out);
}

// Round 11
// 246.412 us; speedup vs baseline: 1.0119x; 1.0119x over previous
//
#include <hip/hip_runtime.h>

#define HW 16384   // 128*128

typedef __attribute__((ext_vector_type(8))) short short8;
typedef __attribute__((ext_vector_type(16))) float floatx16;
typedef __attribute__((ext_vector_type(4))) unsigned int uvec4;

__device__ inline unsigned short f2bf(float f) {
    unsigned u = __builtin_bit_cast(unsigned, f);
    u = (u + 0x7FFFu + ((u >> 16) & 1u)) >> 16;   // RNE
    return (unsigned short)u;
}

// pack two fp32 -> bf16x2 by truncation: one v_perm_b32
__device__ inline unsigned pack_bf_trunc(float lo, float hi) {
    return __builtin_amdgcn_perm(__builtin_bit_cast(unsigned, hi),
                                 __builtin_bit_cast(unsigned, lo), 0x07060302u);
}

__device__ inline unsigned short trunc_bf(float f) {
    return (unsigned short)(__builtin_bit_cast(unsigned, f) >> 16);
}

// ---------------------------------------------------------------------------
// Cast + transpose x -> TWO pixel layouts:
//   xt [b][p =y*128+x][c]  (row-major pixels)
//   xtc[b][pT=x*128+y][c]  (col-major pixels)  <- makes fused side-1 staging
//                                                 CONTIGUOUS (R10: column
//                                                 gathers were 154MB FETCH,
//                                                 0.9TB/s scatter-bound)
// Folds the W-cast into 80 of the 4096 blocks: Wb[320][256] bf16,
// rows 0-31 q (PRE-SCALED by log2e), 32-63 k, 64-319 v.
// ---------------------------------------------------------------------------
__global__ __launch_bounds__(256) void cast_xt_kernel(
    const float* __restrict__ x,
    const float* __restrict__ Wq, const float* __restrict__ Wk,
    const float* __restrict__ Wv, unsigned short* __restrict__ Wb,
    unsigned short* __restrict__ xt, unsigned short* __restrict__ xtc)
{
    __shared__ unsigned short T[64][66];
    const int tid = threadIdx.x;
    const int p0 = blockIdx.x * 64;
    const int c0 = blockIdx.y * 64;
    const int b  = blockIdx.z;

    if (b == 0 && blockIdx.y == 0 && blockIdx.x < 80) {   // folded castW
        int e0 = (blockIdx.x * 256 + tid) * 4;
        int row = e0 >> 8, col = e0 & 255;
        const float* src = (row < 32) ? (Wq + row * 256 + col)
                         : (row < 64) ? (Wk + (row - 32) * 256 + col)
                                      : (Wv + (row - 64) * 256 + col);
        float4 v = *(const float4*)src;
        if (row < 32) {   // q rows: fold log2(e)
            const float L2E = 1.4426950408889634f;
            v.x *= L2E; v.y *= L2E; v.z *= L2E; v.w *= L2E;
        }
        uint2 pk;
        pk.x = f2bf(v.x) | ((unsigned)f2bf(v.y) << 16);
        pk.y = f2bf(v.z) | ((unsigned)f2bf(v.w) << 16);
        *(uint2*)&Wb[e0] = pk;
    }

    #pragma unroll
    for (int i = 0; i < 4; i++) {
        int e = i * 256 + tid;
        int c = e >> 4, seg = e & 15;
        float4 v = *(const float4*)&x[((b * 256 + c0 + c) << 14) + p0 + seg * 4];
        ((unsigned*)&T[c][seg * 4])[0] = f2bf(v.x) | ((unsigned)f2bf(v.y) << 16);
        ((unsigned*)&T[c][seg * 4])[1] = f2bf(v.z) | ((unsigned)f2bf(v.w) << 16);
    }
    __syncthreads();
    #pragma unroll
    for (int i = 0; i < 2; i++) {
        int e = i * 256 + tid;
        int p = e >> 3, cs = e & 7;
        unsigned short t[8];
        #pragma unroll
        for (int j = 0; j < 8; j++) t[j] = T[cs * 8 + j][p];
        uint4 pk;
        pk.x = t[0] | ((unsigned)t[1] << 16);
        pk.y = t[2] | ((unsigned)t[3] << 16);
        pk.z = t[4] | ((unsigned)t[5] << 16);
        pk.w = t[6] | ((unsigned)t[7] << 16);
        int pix = p0 + p;
        int pT  = ((pix & 127) << 7) | (pix >> 7);   // (y,x) -> (x,y)
        *(uint4*)&xt [(((b << 14) + pix) << 8) + c0 + cs * 8] = pk;
        *(uint4*)&xtc[(((b << 14) + pT ) << 8) + c0 + cs * 8] = pk;
    }
}

// ---------------------------------------------------------------------------
// FUSED proj+attention v6. vs R10 v5b (169us, HBM-scatter-bound):
//  - side-1 stages from xtc (contiguous 64KB panel, same index as side-0,
//    different base) -> no 64KB-stride column gathers.
//  - XCD chunk swizzle: logical=(bid&7)*256+(bid>>3) -> the 16 bh-sharers of
//    each y (which read IDENTICAL xt/xtc panels) and consecutive y co-locate
//    on one XCD L2 -> panel fetched ~once per XCD.
//  - single Vs buffer (16KB): side-1's kc-loop barriers already separate
//    side-0 Vs reads from side-1 Vs writes. LDS 51.7->35KB -> 4 blocks/CU.
// Proj/extract/attention math identical to R10 (verified, absmax 0.047).
// ---------------------------------------------------------------------------
__global__ __launch_bounds__(256, 2) void fused_kernel(
    const unsigned short* __restrict__ Wb, const unsigned short* __restrict__ xt,
    const unsigned short* __restrict__ xtc,
    const float* __restrict__ bq, const float* __restrict__ bk,
    const float* __restrict__ bv,
    const float* __restrict__ xin, const float* __restrict__ gamma,
    float* __restrict__ out)
{
    __shared__ __align__(16) unsigned short XTS[128 * 64];   // 16KB xt panel
    __shared__ __align__(16) unsigned short Vs[64 * 128];    // 16KB [ch][key]
    __shared__ __align__(16) unsigned short Kl[128 * 8];     // 2KB [px][8ch]
    __shared__ float biasS[80];                              // q8|k8|v64

    const int tid = threadIdx.x;
    // XCD chunk swizzle: XCD k owns y in [16k,16k+16), all 16 bh per y.
    const int logical = (blockIdx.x & 7) * 256 + (blockIdx.x >> 3);
    const int bh = logical & 15, y = logical >> 4;
    const int b = bh >> 2, h = bh & 3;
    const int w = tid >> 6, l = tid & 63, lr = l & 31, lh = l >> 5;
    const int px = 32 * w + lr;

    if (tid < 80) biasS[tid] = (tid < 8)  ? bq[h * 8 + tid] * 1.4426950408889634f
                             : (tid < 16) ? bk[h * 8 + tid - 8]
                                          : bv[h * 64 + tid - 16];

    // per-lane W row indices for the 3 A-tiles
    const int wr0 = (lr < 8)  ? h * 8 + lr
                  : (lr < 16) ? 32 + h * 8 + (lr - 8)
                              : 64 + h * 64 + (lr - 16);
    const int wr1 = 64 + h * 64 + 16 + lr;
    const int wr2 = 64 + h * 64 + 48 + (lr & 15);   // lr>=16: junk rows (discarded)

    floatx16 z16 = {0,0,0,0,0,0,0,0,0,0,0,0,0,0,0,0};
    short8 z8 = {0,0,0,0,0,0,0,0};
    floatx16 oh0 = z16, oh1 = z16, ov0 = z16, ov1 = z16;
    float ssA = 1.0f, ssB = 1.0f;

    #pragma unroll
    for (int side = 0; side < 2; side++) {
        // ---------------- projection: K=256 reduction ----------------
        const unsigned short* xsrc = side ? xtc : xt;   // both: contiguous panel
        floatx16 a0 = z16, a1 = z16, a2 = z16;
        for (int kc = 0; kc < 4; kc++) {
            __syncthreads();   // XTS (and cross-side Vs/Kl) safe to write
            #pragma unroll
            for (int i = 0; i < 4; i++) {
                int e = i * 256 + tid;
                int row = e >> 3, seg = e & 7, cp = seg ^ (row & 7);
                *(uint4*)&XTS[row * 64 + cp * 8] =
                    *(const uint4*)&xsrc[(((b << 14) + y * 128 + row) << 8) + kc * 64 + seg * 8];
            }
            __syncthreads();
            #pragma unroll
            for (int ks = 0; ks < 4; ks++) {   // 4 -> full 64ch per kc
                int cx = ((2 * ks + lh) ^ (lr & 7)) * 8;
                short8 bfr = *(const short8*)&XTS[px * 64 + cx];
                int ck = kc * 64 + (2 * ks + lh) * 8;
                short8 af0 = *(const short8*)&Wb[wr0 * 256 + ck];
                short8 af1 = *(const short8*)&Wb[wr1 * 256 + ck];
                short8 af2 = *(const short8*)&Wb[wr2 * 256 + ck];
                a0 = __builtin_amdgcn_mfma_f32_32x32x16_bf16(af0, bfr, a0, 0, 0, 0);
                a1 = __builtin_amdgcn_mfma_f32_32x32x16_bf16(af1, bfr, a1, 0, 0, 0);
                a2 = __builtin_amdgcn_mfma_f32_32x32x16_bf16(af2, bfr, a2, 0, 0, 0);
            }
        }
        // ---------------- extract q / k / v ----------------
        // q: tile0 rows 0-7 = regs 0-3 (+4lh). lh=0 lane needs ch0-7:
        // words = [own(ch 0-3), partner(ch 4-7)] via shfl_xor(32).
        unsigned X0 = pack_bf_trunc(a0[0] + biasS[4 * lh + 0], a0[1] + biasS[4 * lh + 1]);
        unsigned X1 = pack_bf_trunc(a0[2] + biasS[4 * lh + 2], a0[3] + biasS[4 * lh + 3]);
        unsigned pX0 = __shfl_xor(X0, 32), pX1 = __shfl_xor(X1, 32);
        short8 bfq = z8;
        if (lh == 0) {
            uvec4 t; t.x = X0; t.y = X1; t.z = pX0; t.w = pX1;
            bfq = __builtin_bit_cast(short8, t);
        }
        // k: tile0 rows 8-15 = regs 4-7 -> Kl[px][8ch] (uint2 per lane, lh-half)
        {
            uint2 kk;
            kk.x = pack_bf_trunc(a0[4] + biasS[8 + 4 * lh + 0], a0[5] + biasS[8 + 4 * lh + 1]);
            kk.y = pack_bf_trunc(a0[6] + biasS[8 + 4 * lh + 2], a0[7] + biasS[8 + 4 * lh + 3]);
            *(uint2*)&Kl[px * 8 + 4 * lh] = kk;
        }
        // v: tile0 rows 16-31 (regs 8-15) = ch 0-15; tile1 = ch 16-47;
        //    tile2 regs 0-7 = ch 48-63. Vs[ch][key px], chunk ^= (ch&15).
        #pragma unroll
        for (int reg = 8; reg < 16; reg++) {
            int ch = (reg & 3) + 8 * ((reg >> 2) - 2) + 4 * lh;
            Vs[ch * 128 + (((px >> 3) ^ (ch & 15)) << 3) + (px & 7)] =
                trunc_bf(a0[reg] + biasS[16 + ch]);
        }
        #pragma unroll
        for (int reg = 0; reg < 16; reg++) {
            int ch = 16 + (reg & 3) + 8 * (reg >> 2) + 4 * lh;
            Vs[ch * 128 + (((px >> 3) ^ (ch & 15)) << 3) + (px & 7)] =
                trunc_bf(a1[reg] + biasS[16 + ch]);
        }
        #pragma unroll
        for (int reg = 0; reg < 8; reg++) {
            int ch = 48 + (reg & 3) + 8 * (reg >> 2) + 4 * lh;
            Vs[ch * 128 + (((px >> 3) ^ (ch & 15)) << 3) + (px & 7)] =
                trunc_bf(a2[reg] + biasS[16 + ch]);
        }
        __syncthreads();   // Kl/Vs visible to all waves
        // ---------------- attention (verified R7/R10 structure) ----------------
        float partial = 0.f;
        #pragma unroll
        for (int kg = 0; kg < 4; kg++) {
            short8 af = z8;
            if (lh == 0) af = *(const short8*)&Kl[(32 * kg + lr) * 8];
            floatx16 e = __builtin_amdgcn_mfma_f32_32x32x16_bf16(af, bfq, z16, 0, 0, 0);
            #pragma unroll
            for (int r = 0; r < 16; r++) {
                float p = exp2f(e[r]);   // L2E folded into q; no max-pass (|e| small)
                e[r] = p;
                partial += p;
            }
            #pragma unroll
            for (int cc = 0; cc < 2; cc++) {
                unsigned Y0 = pack_bf_trunc(e[8*cc+0], e[8*cc+1]);
                unsigned Y1 = pack_bf_trunc(e[8*cc+2], e[8*cc+3]);
                unsigned Y2 = pack_bf_trunc(e[8*cc+4], e[8*cc+5]);
                unsigned Y3 = pack_bf_trunc(e[8*cc+6], e[8*cc+7]);
                unsigned pY0 = __shfl_xor(Y0, 32);
                unsigned pY1 = __shfl_xor(Y1, 32);
                unsigned pY2 = __shfl_xor(Y2, 32);
                unsigned pY3 = __shfl_xor(Y3, 32);
                uvec4 t;
                t.x = lh ? pY2 : Y0;
                t.y = lh ? pY3 : Y1;
                t.z = lh ? Y2  : pY0;
                t.w = lh ? Y3  : pY1;
                short8 pf = __builtin_bit_cast(short8, t);
                int ks = 2 * kg + cc;
                int cp = ((2 * ks + lh) ^ (lr & 15)) * 8;
                short8 v0 = *(const short8*)&Vs[lr * 128 + cp];
                short8 v1 = *(const short8*)&Vs[(32 + lr) * 128 + cp];
                if (side == 0) {
                    oh0 = __builtin_amdgcn_mfma_f32_32x32x16_bf16(v0, pf, oh0, 0, 0, 0);
                    oh1 = __builtin_amdgcn_mfma_f32_32x32x16_bf16(v1, pf, oh1, 0, 0, 0);
                } else {
                    ov0 = __builtin_amdgcn_mfma_f32_32x32x16_bf16(v0, pf, ov0, 0, 0, 0);
                    ov1 = __builtin_amdgcn_mfma_f32_32x32x16_bf16(v1, pf, ov1, 0, 0, 0);
                }
            }
        }
        float ssum = partial + __shfl_xor(partial, 32);
        if (side == 0) ssA = ssum; else ssB = ssum;
    }

    __syncthreads();   // re-converge waves: adjacent 128B out-stores coalesce

    const float g  = gamma[0];
    const float g0 = g / ssA, g1 = g / ssB;
    #pragma unroll
    for (int reg = 0; reg < 16; reg++) {
        int ch = (reg & 3) + 8 * (reg >> 2) + 4 * lh;
        int idx0 = (bh * 64 + ch) * HW + y * 128 + px;
        int idx1 = (bh * 64 + 32 + ch) * HW + y * 128 + px;
        out[idx0] = g0 * oh0[reg] + g1 * ov0[reg] + xin[idx0];
        out[idx1] = g0 * oh1[reg] + g1 * ov1[reg] + xin[idx1];
    }
}

extern "C" void kernel_launch(void* const* d_in, const int* in_sizes, int n_in,
                              void* d_out, int out_size, void* d_ws, size_t ws_size,
                              hipStream_t stream) {
    const float* x     = (const float*)d_in[0];
    const float* Wq    = (const float*)d_in[1];
    const float* bq    = (const float*)d_in[2];
    const float* Wk    = (const float*)d_in[3];
    const float* bk    = (const float*)d_in[4];
    const float* Wv    = (const float*)d_in[5];
    const float* bv    = (const float*)d_in[6];
    const float* gamma = (const float*)d_in[7];
    float* out = (float*)d_out;

    unsigned short* Wb  = (unsigned short*)d_ws;
    unsigned short* xt  = Wb + 320 * 256;      // 32MB
    unsigned short* xtc = xt + 4 * HW * 256;   // 32MB, pixel-transposed copy

    cast_xt_kernel<<<dim3(256, 4, 4), 256, 0, stream>>>(x, Wq, Wk, Wv, Wb, xt, xtc);
    fused_kernel<<<dim3(2048), 256, 0, stream>>>(Wb, xt, xtc, bq, bk, bv, x, gamma, out);
}

// Round 12
// 206.772 us; speedup vs baseline: 1.2059x; 1.1917x over previous
//
#include <hip/hip_runtime.h>

#define HW 16384   // 128*128

typedef __attribute__((ext_vector_type(8))) short short8;
typedef __attribute__((ext_vector_type(16))) float floatx16;
typedef __attribute__((ext_vector_type(4))) unsigned int uvec4;

__device__ inline unsigned short f2bf(float f) {
    unsigned u = __builtin_bit_cast(unsigned, f);
    u = (u + 0x7FFFu + ((u >> 16) & 1u)) >> 16;   // RNE
    return (unsigned short)u;
}

// pack two fp32 -> bf16x2 by truncation: one v_perm_b32
__device__ inline unsigned pack_bf_trunc(float lo, float hi) {
    return __builtin_amdgcn_perm(__builtin_bit_cast(unsigned, hi),
                                 __builtin_bit_cast(unsigned, lo), 0x07060302u);
}

__device__ inline unsigned short trunc_bf(float f) {
    return (unsigned short)(__builtin_bit_cast(unsigned, f) >> 16);
}

// ---------------------------------------------------------------------------
// Cast + transpose x: [b][c][p] fp32 -> xt[b][p][c] bf16 (coalesced only —
// R11's in-cast xtc writes were 16B pieces at 64KB stride = ~110us).
// Folds the W-cast into 80 of the 4096 blocks: Wb[320][256] bf16,
// rows 0-31 q (PRE-SCALED by log2e), 32-63 k, 64-319 v.
// ---------------------------------------------------------------------------
__global__ __launch_bounds__(256) void cast_xt_kernel(
    const float* __restrict__ x,
    const float* __restrict__ Wq, const float* __restrict__ Wk,
    const float* __restrict__ Wv, unsigned short* __restrict__ Wb,
    unsigned short* __restrict__ xt)
{
    __shared__ unsigned short T[64][66];
    const int tid = threadIdx.x;
    const int p0 = blockIdx.x * 64;
    const int c0 = blockIdx.y * 64;
    const int b  = blockIdx.z;

    if (b == 0 && blockIdx.y == 0 && blockIdx.x < 80) {   // folded castW
        int e0 = (blockIdx.x * 256 + tid) * 4;
        int row = e0 >> 8, col = e0 & 255;
        const float* src = (row < 32) ? (Wq + row * 256 + col)
                         : (row < 64) ? (Wk + (row - 32) * 256 + col)
                                      : (Wv + (row - 64) * 256 + col);
        float4 v = *(const float4*)src;
        if (row < 32) {   // q rows: fold log2(e)
            const float L2E = 1.4426950408889634f;
            v.x *= L2E; v.y *= L2E; v.z *= L2E; v.w *= L2E;
        }
        uint2 pk;
        pk.x = f2bf(v.x) | ((unsigned)f2bf(v.y) << 16);
        pk.y = f2bf(v.z) | ((unsigned)f2bf(v.w) << 16);
        *(uint2*)&Wb[e0] = pk;
    }

    #pragma unroll
    for (int i = 0; i < 4; i++) {
        int e = i * 256 + tid;
        int c = e >> 4, seg = e & 15;
        float4 v = *(const float4*)&x[((b * 256 + c0 + c) << 14) + p0 + seg * 4];
        ((unsigned*)&T[c][seg * 4])[0] = f2bf(v.x) | ((unsigned)f2bf(v.y) << 16);
        ((unsigned*)&T[c][seg * 4])[1] = f2bf(v.z) | ((unsigned)f2bf(v.w) << 16);
    }
    __syncthreads();
    #pragma unroll
    for (int i = 0; i < 2; i++) {
        int e = i * 256 + tid;
        int p = e >> 3, cs = e & 7;
        unsigned short t[8];
        #pragma unroll
        for (int j = 0; j < 8; j++) t[j] = T[cs * 8 + j][p];
        uint4 pk;
        pk.x = t[0] | ((unsigned)t[1] << 16);
        pk.y = t[2] | ((unsigned)t[3] << 16);
        pk.z = t[4] | ((unsigned)t[5] << 16);
        pk.w = t[6] | ((unsigned)t[7] << 16);
        *(uint4*)&xt[(((b << 14) + p0 + p) << 8) + c0 + cs * 8] = pk;
    }
}

// ---------------------------------------------------------------------------
// Pixel-record transpose xt -> xtc: record = 512B (256ch bf16).
// Block (x0, b): reads 128 records xt[y*128+x0] (512B contiguous each,
// 64KB stride), writes xtc[x0*128+y] = one CONTIGUOUS 64KB run.
// ---------------------------------------------------------------------------
__global__ __launch_bounds__(256) void tpx_kernel(
    const unsigned short* __restrict__ xt, unsigned short* __restrict__ xtc)
{
    const int x0 = blockIdx.x;    // 0..127
    const int b  = blockIdx.y;    // 0..3
    const int tid = threadIdx.x;
    const int r = tid >> 5, cseg = tid & 31;   // 8 records / iteration
    #pragma unroll
    for (int i = 0; i < 16; i++) {
        int y = i * 8 + r;
        uint4 v = *(const uint4*)&xt[(((b << 14) + y * 128 + x0) << 8) + cseg * 8];
        *(uint4*)&xtc[(((b << 14) + x0 * 128 + y) << 8) + cseg * 8] = v;
    }
}

// ---------------------------------------------------------------------------
// FUSED proj+attention v7. vs R11 v6 (135us, 70% stall):
//  - W rows for this head (q8+k8+v64 = 80 rows, 40KB) staged into Ws LDS
//    ONCE, XOR-swizzled (chunk c ^= row&7) -> proj inner loop is pure LDS;
//    removes 96 global-load latencies per thread from the barrier-serialized
//    phase chain (R11 read af0-2 from global INSIDE the MFMA loop).
//    Local row map: tile0 -> lr, tile1 -> 32+lr, tile2 -> 64+(lr&15).
//  - everything else identical to R11 (verified absmax 0.047).
// LDS: 40960(Ws) + 16384(XTS) + 16384(Vs) + 2048(Kl) + 320 = ~75KB -> 2/CU.
// ---------------------------------------------------------------------------
__global__ __launch_bounds__(256, 2) void fused_kernel(
    const unsigned short* __restrict__ Wb, const unsigned short* __restrict__ xt,
    const unsigned short* __restrict__ xtc,
    const float* __restrict__ bq, const float* __restrict__ bk,
    const float* __restrict__ bv,
    const float* __restrict__ xin, const float* __restrict__ gamma,
    float* __restrict__ out)
{
    __shared__ __align__(16) unsigned short Ws[80 * 256];    // 40KB W rows
    __shared__ __align__(16) unsigned short XTS[128 * 64];   // 16KB xt panel
    __shared__ __align__(16) unsigned short Vs[64 * 128];    // 16KB [ch][key]
    __shared__ __align__(16) unsigned short Kl[128 * 8];     // 2KB [px][8ch]
    __shared__ float biasS[80];                              // q8|k8|v64

    const int tid = threadIdx.x;
    // XCD chunk swizzle: XCD k owns y in [16k,16k+16), all 16 bh per y.
    const int logical = (blockIdx.x & 7) * 256 + (blockIdx.x >> 3);
    const int bh = logical & 15, y = logical >> 4;
    const int b = bh >> 2, h = bh & 3;
    const int w = tid >> 6, l = tid & 63, lr = l & 31, lh = l >> 5;
    const int px = 32 * w + lr;

    if (tid < 80) biasS[tid] = (tid < 8)  ? bq[h * 8 + tid] * 1.4426950408889634f
                             : (tid < 16) ? bk[h * 8 + tid - 8]
                                          : bv[h * 64 + tid - 16];

    // stage W rows: local [0-7]=q(h), [8-15]=k(h), [16-79]=v(h); chunk^=(R&7)
    #pragma unroll
    for (int i = 0; i < 10; i++) {
        int e = i * 256 + tid;            // 2560 chunk-copies of 16B
        int R = e >> 5, c = e & 31, cp = c ^ (R & 7);
        int gr = (R < 8)  ? h * 8 + R
               : (R < 16) ? 32 + h * 8 + (R - 8)
                          : 64 + h * 64 + (R - 16);
        *(uint4*)&Ws[R * 256 + cp * 8] = *(const uint4*)&Wb[gr * 256 + c * 8];
    }

    floatx16 z16 = {0,0,0,0,0,0,0,0,0,0,0,0,0,0,0,0};
    short8 z8 = {0,0,0,0,0,0,0,0};
    floatx16 oh0 = z16, oh1 = z16, ov0 = z16, ov1 = z16;
    float ssA = 1.0f, ssB = 1.0f;

    #pragma unroll
    for (int side = 0; side < 2; side++) {
        // ---------------- projection: K=256 reduction ----------------
        const unsigned short* xsrc = side ? xtc : xt;   // both: contiguous panel
        floatx16 a0 = z16, a1 = z16, a2 = z16;
        for (int kc = 0; kc < 4; kc++) {
            __syncthreads();   // XTS (and Ws at first iter / cross-side Vs,Kl) ready
            #pragma unroll
            for (int i = 0; i < 4; i++) {
                int e = i * 256 + tid;
                int row = e >> 3, seg = e & 7, cp = seg ^ (row & 7);
                *(uint4*)&XTS[row * 64 + cp * 8] =
                    *(const uint4*)&xsrc[(((b << 14) + y * 128 + row) << 8) + kc * 64 + seg * 8];
            }
            __syncthreads();
            #pragma unroll
            for (int ks = 0; ks < 4; ks++) {   // full 64ch per kc
                int cx = ((2 * ks + lh) ^ (lr & 7)) * 8;
                short8 bfr = *(const short8*)&XTS[px * 64 + cx];
                int ci = kc * 8 + 2 * ks + lh;
                int cwp = (ci ^ (lr & 7)) * 8;
                short8 af0 = *(const short8*)&Ws[lr * 256 + cwp];
                short8 af1 = *(const short8*)&Ws[(32 + lr) * 256 + cwp];
                short8 af2 = *(const short8*)&Ws[(64 + (lr & 15)) * 256 + cwp];
                a0 = __builtin_amdgcn_mfma_f32_32x32x16_bf16(af0, bfr, a0, 0, 0, 0);
                a1 = __builtin_amdgcn_mfma_f32_32x32x16_bf16(af1, bfr, a1, 0, 0, 0);
                a2 = __builtin_amdgcn_mfma_f32_32x32x16_bf16(af2, bfr, a2, 0, 0, 0);
            }
        }
        // ---------------- extract q / k / v ----------------
        // q: tile0 rows 0-7 = regs 0-3 (+4lh). lh=0 lane needs ch0-7:
        // words = [own(ch 0-3), partner(ch 4-7)] via shfl_xor(32).
        unsigned X0 = pack_bf_trunc(a0[0] + biasS[4 * lh + 0], a0[1] + biasS[4 * lh + 1]);
        unsigned X1 = pack_bf_trunc(a0[2] + biasS[4 * lh + 2], a0[3] + biasS[4 * lh + 3]);
        unsigned pX0 = __shfl_xor(X0, 32), pX1 = __shfl_xor(X1, 32);
        short8 bfq = z8;
        if (lh == 0) {
            uvec4 t; t.x = X0; t.y = X1; t.z = pX0; t.w = pX1;
            bfq = __builtin_bit_cast(short8, t);
        }
        // k: tile0 rows 8-15 = regs 4-7 -> Kl[px][8ch] (uint2 per lane, lh-half)
        {
            uint2 kk;
            kk.x = pack_bf_trunc(a0[4] + biasS[8 + 4 * lh + 0], a0[5] + biasS[8 + 4 * lh + 1]);
            kk.y = pack_bf_trunc(a0[6] + biasS[8 + 4 * lh + 2], a0[7] + biasS[8 + 4 * lh + 3]);
            *(uint2*)&Kl[px * 8 + 4 * lh] = kk;
        }
        // v: tile0 rows 16-31 (regs 8-15) = ch 0-15; tile1 = ch 16-47;
        //    tile2 regs 0-7 = ch 48-63. Vs[ch][key px], chunk ^= (ch&15).
        #pragma unroll
        for (int reg = 8; reg < 16; reg++) {
            int ch = (reg & 3) + 8 * ((reg >> 2) - 2) + 4 * lh;
            Vs[ch * 128 + (((px >> 3) ^ (ch & 15)) << 3) + (px & 7)] =
                trunc_bf(a0[reg] + biasS[16 + ch]);
        }
        #pragma unroll
        for (int reg = 0; reg < 16; reg++) {
            int ch = 16 + (reg & 3) + 8 * (reg >> 2) + 4 * lh;
            Vs[ch * 128 + (((px >> 3) ^ (ch & 15)) << 3) + (px & 7)] =
                trunc_bf(a1[reg] + biasS[16 + ch]);
        }
        #pragma unroll
        for (int reg = 0; reg < 8; reg++) {
            int ch = 48 + (reg & 3) + 8 * (reg >> 2) + 4 * lh;
            Vs[ch * 128 + (((px >> 3) ^ (ch & 15)) << 3) + (px & 7)] =
                trunc_bf(a2[reg] + biasS[16 + ch]);
        }
        __syncthreads();   // Kl/Vs visible to all waves
        // ---------------- attention (verified R7/R10 structure) ----------------
        float partial = 0.f;
        #pragma unroll
        for (int kg = 0; kg < 4; kg++) {
            short8 af = z8;
            if (lh == 0) af = *(const short8*)&Kl[(32 * kg + lr) * 8];
            floatx16 e = __builtin_amdgcn_mfma_f32_32x32x16_bf16(af, bfq, z16, 0, 0, 0);
            #pragma unroll
            for (int r = 0; r < 16; r++) {
                float p = exp2f(e[r]);   // L2E folded into q; no max-pass (|e| small)
                e[r] = p;
                partial += p;
            }
            #pragma unroll
            for (int cc = 0; cc < 2; cc++) {
                unsigned Y0 = pack_bf_trunc(e[8*cc+0], e[8*cc+1]);
                unsigned Y1 = pack_bf_trunc(e[8*cc+2], e[8*cc+3]);
                unsigned Y2 = pack_bf_trunc(e[8*cc+4], e[8*cc+5]);
                unsigned Y3 = pack_bf_trunc(e[8*cc+6], e[8*cc+7]);
                unsigned pY0 = __shfl_xor(Y0, 32);
                unsigned pY1 = __shfl_xor(Y1, 32);
                unsigned pY2 = __shfl_xor(Y2, 32);
                unsigned pY3 = __shfl_xor(Y3, 32);
                uvec4 t;
                t.x = lh ? pY2 : Y0;
                t.y = lh ? pY3 : Y1;
                t.z = lh ? Y2  : pY0;
                t.w = lh ? Y3  : pY1;
                short8 pf = __builtin_bit_cast(short8, t);
                int ks = 2 * kg + cc;
                int cp = ((2 * ks + lh) ^ (lr & 15)) * 8;
                short8 v0 = *(const short8*)&Vs[lr * 128 + cp];
                short8 v1 = *(const short8*)&Vs[(32 + lr) * 128 + cp];
                if (side == 0) {
                    oh0 = __builtin_amdgcn_mfma_f32_32x32x16_bf16(v0, pf, oh0, 0, 0, 0);
                    oh1 = __builtin_amdgcn_mfma_f32_32x32x16_bf16(v1, pf, oh1, 0, 0, 0);
                } else {
                    ov0 = __builtin_amdgcn_mfma_f32_32x32x16_bf16(v0, pf, ov0, 0, 0, 0);
                    ov1 = __builtin_amdgcn_mfma_f32_32x32x16_bf16(v1, pf, ov1, 0, 0, 0);
                }
            }
        }
        float ssum = partial + __shfl_xor(partial, 32);
        if (side == 0) ssA = ssum; else ssB = ssum;
    }

    __syncthreads();   // re-converge waves: adjacent 128B out-stores coalesce

    const float g  = gamma[0];
    const float g0 = g / ssA, g1 = g / ssB;
    #pragma unroll
    for (int reg = 0; reg < 16; reg++) {
        int ch = (reg & 3) + 8 * (reg >> 2) + 4 * lh;
        int idx0 = (bh * 64 + ch) * HW + y * 128 + px;
        int idx1 = (bh * 64 + 32 + ch) * HW + y * 128 + px;
        out[idx0] = g0 * oh0[reg] + g1 * ov0[reg] + xin[idx0];
        out[idx1] = g0 * oh1[reg] + g1 * ov1[reg] + xin[idx1];
    }
}

extern "C" void kernel_launch(void* const* d_in, const int* in_sizes, int n_in,
                              void* d_out, int out_size, void* d_ws, size_t ws_size,
                              hipStream_t stream) {
    const float* x     = (const float*)d_in[0];
    const float* Wq    = (const float*)d_in[1];
    const float* bq    = (const float*)d_in[2];
    const float* Wk    = (const float*)d_in[3];
    const float* bk    = (const float*)d_in[4];
    const float* Wv    = (const float*)d_in[5];
    const float* bv    = (const float*)d_in[6];
    const float* gamma = (const float*)d_in[7];
    float* out = (float*)d_out;

    unsigned short* Wb  = (unsigned short*)d_ws;
    unsigned short* xt  = Wb + 320 * 256;      // 32MB
    unsigned short* xtc = xt + 4 * HW * 256;   // 32MB, pixel-transposed copy

    cast_xt_kernel<<<dim3(256, 4, 4), 256, 0, stream>>>(x, Wq, Wk, Wv, Wb, xt);
    tpx_kernel<<<dim3(128, 4), 256, 0, stream>>>(xt, xtc);
    fused_kernel<<<dim3(2048), 256, 0, stream>>>(Wb, xt, xtc, bq, bk, bv, x, gamma, out);
}